// Round 1
// baseline (1330.629 us; speedup 1.0000x reference)
//
#include <hip/hip_runtime.h>
#include <hip/hip_bf16.h>

#define N_NODES_C 100000
#define N_EDGES_C 150000
#define DC 512
#define NG 64

typedef float f32x4 __attribute__((ext_vector_type(4)));
typedef short s16x8 __attribute__((ext_vector_type(8)));

__device__ __forceinline__ short f2bf(float f) {
    union { float f; unsigned u; } c; c.f = f;
    unsigned r = c.u + 0x7fffu + ((c.u >> 16) & 1u);
    return (short)(r >> 16);
}

// ---------------- small kernels ----------------

__global__ void zero_k(float* s, float* aggs, float* gsum, float* gcnt) {
    int i = blockIdx.x * 256 + threadIdx.x;
    if (i < N_NODES_C) { s[i] = 0.f; aggs[i] = 0.f; }
    if (i < NG) { gsum[i] = 0.f; gcnt[i] = 0.f; }
}

// out[n][k] = bf16(in[k][n]); in is [512][512] f32 row-major
__global__ void transpose_w(const float* __restrict__ in, short* __restrict__ out) {
    __shared__ float tile[32][33];
    int tx = threadIdx.x & 31;
    int ty = threadIdx.x >> 5;  // 0..7
    int k0 = blockIdx.y * 32;
    int n0 = blockIdx.x * 32;
#pragma unroll
    for (int i = 0; i < 4; ++i)
        tile[ty + i * 8][tx] = in[(size_t)(k0 + ty + i * 8) * DC + n0 + tx];
    __syncthreads();
#pragma unroll
    for (int i = 0; i < 4; ++i)
        out[(size_t)(n0 + ty + i * 8) * DC + k0 + tx] = f2bf(tile[tx][ty + i * 8]);
}

__global__ void copy_f4(const float* __restrict__ x, float* __restrict__ z, int n4) {
    int i = blockIdx.x * blockDim.x + threadIdx.x;
    int stride = gridDim.x * blockDim.x;
    const f32x4* xs = (const f32x4*)x;
    f32x4* zs = (f32x4*)z;
    for (; i < n4; i += stride) zs[i] = xs[i];
}

// z[dst] += x[src] (512-wide rows). 2 edges per 256-thread block, 128 threads/edge.
__global__ void scatter_rows(const float* __restrict__ x, const int* __restrict__ ei,
                             float* __restrict__ z) {
    int e = blockIdx.x * 2 + (threadIdx.x >> 7);
    if (e >= N_EDGES_C) return;
    int t = threadIdx.x & 127;
    int si = ei[e];
    int di = ei[N_EDGES_C + e];
    f32x4 v = *(const f32x4*)(x + (size_t)si * DC + t * 4);
    float* zp = z + (size_t)di * DC + t * 4;
    atomicAdd(zp + 0, v.x);
    atomicAdd(zp + 1, v.y);
    atomicAdd(zp + 2, v.z);
    atomicAdd(zp + 3, v.w);
}

__global__ void edge_scalar(const int* __restrict__ ei, const float* __restrict__ s,
                            float* __restrict__ aggs) {
    int e = blockIdx.x * 256 + threadIdx.x;
    if (e < N_EDGES_C) atomicAdd(&aggs[ei[N_EDGES_C + e]], s[ei[e]]);
}

__global__ void node_pool(const float* __restrict__ s, const float* __restrict__ aggs,
                          const int* __restrict__ batch, const float* __restrict__ b2a,
                          float* __restrict__ gsum, float* __restrict__ gcnt) {
    __shared__ float ls[NG], lc[NG];
    int t = threadIdx.x;
    if (t < NG) { ls[t] = 0.f; lc[t] = 0.f; }
    __syncthreads();
    int i = blockIdx.x * 256 + t;
    if (i < N_NODES_C) {
        float z2 = fmaxf(aggs[i] + s[i] + b2a[0], 0.0f);
        int g = batch[i];
        atomicAdd(&ls[g], z2);
        atomicAdd(&lc[g], 1.0f);
    }
    __syncthreads();
    if (t < NG && lc[t] != 0.f) {
        atomicAdd(&gsum[t], ls[t]);
        atomicAdd(&gcnt[t], lc[t]);
    }
}

__global__ void finalize_k(const float* gsum, const float* gcnt, const float* w2b,
                           const float* b2b, float* out) {
    int g = threadIdx.x;
    if (g < NG) {
        float c = fmaxf(gcnt[g], 1.0f);
        out[g] = gsum[g] / c * w2b[0] + b2b[0];
    }
}

// ---------------- GEMM ----------------
// MODE 0: A = f32 z (convert to bf16 in staging); C = relu(A@W + bias) -> bf16 z1
// MODE 1: A = bf16 z1; epilogue: h = relu(A@W + bias); s[row] += h . w2a (atomic)
#define BM 128
#define BN 128
#define BK 32
#define LDK 40  // 32 + 8-short pad -> 80B row stride, ~2-way bank aliasing (free)

template <int MODE>
__global__ __launch_bounds__(256, 2) void gemm_k(const void* __restrict__ Ap,
                                                 const short* __restrict__ Bt,
                                                 const float* __restrict__ bias,
                                                 short* __restrict__ Cout,
                                                 const float* __restrict__ w2a,
                                                 float* __restrict__ s_out) {
    __shared__ alignas(16) short As[BM * LDK];
    __shared__ alignas(16) short Bs[BN * LDK];

    const int tid  = threadIdx.x;
    const int brow = blockIdx.y * BM;
    const int bcol = blockIdx.x * BN;

    const int lane = tid & 63;
    const int wr   = (tid >> 7) * 64;        // wave row (waves {0,1}->0, {2,3}->64)
    const int wc   = ((tid >> 6) & 1) * 64;  // wave col
    const int lr   = lane & 15;
    const int lk   = (lane >> 4) * 8;

    f32x4 acc[4][4] = {};

    const int str = tid >> 1;        // staging row/col 0..127
    const int skk = (tid & 1) * 16;  // element offset within the 32-wide K slab
    int arow = brow + str;
    if (arow >= N_NODES_C) arow = N_NODES_C - 1;  // clamp loads; stores guarded

    const short* bgp = Bt + (size_t)(bcol + str) * DC + skk;

    for (int kt = 0; kt < DC / BK; ++kt) {
        const int k0 = kt * BK;
        short areg[16];
        if constexpr (MODE == 0) {
            const float* ap = (const float*)Ap + (size_t)arow * DC + k0 + skk;
            f32x4 a0 = *(const f32x4*)(ap + 0);
            f32x4 a1 = *(const f32x4*)(ap + 4);
            f32x4 a2 = *(const f32x4*)(ap + 8);
            f32x4 a3 = *(const f32x4*)(ap + 12);
            areg[0]  = f2bf(a0.x); areg[1]  = f2bf(a0.y); areg[2]  = f2bf(a0.z); areg[3]  = f2bf(a0.w);
            areg[4]  = f2bf(a1.x); areg[5]  = f2bf(a1.y); areg[6]  = f2bf(a1.z); areg[7]  = f2bf(a1.w);
            areg[8]  = f2bf(a2.x); areg[9]  = f2bf(a2.y); areg[10] = f2bf(a2.z); areg[11] = f2bf(a2.w);
            areg[12] = f2bf(a3.x); areg[13] = f2bf(a3.y); areg[14] = f2bf(a3.z); areg[15] = f2bf(a3.w);
        } else {
            const short* ap = (const short*)Ap + (size_t)arow * DC + k0 + skk;
            *(s16x8*)&areg[0] = *(const s16x8*)(ap + 0);
            *(s16x8*)&areg[8] = *(const s16x8*)(ap + 8);
        }
        s16x8 b0 = *(const s16x8*)(bgp + k0);
        s16x8 b1 = *(const s16x8*)(bgp + k0 + 8);

        __syncthreads();
        *(s16x8*)&As[str * LDK + skk + 0] = *(s16x8*)&areg[0];
        *(s16x8*)&As[str * LDK + skk + 8] = *(s16x8*)&areg[8];
        *(s16x8*)&Bs[str * LDK + skk + 0] = b0;
        *(s16x8*)&Bs[str * LDK + skk + 8] = b1;
        __syncthreads();

        s16x8 af[4], bf[4];
#pragma unroll
        for (int mi = 0; mi < 4; ++mi)
            af[mi] = *(const s16x8*)&As[(wr + mi * 16 + lr) * LDK + lk];
#pragma unroll
        for (int ni = 0; ni < 4; ++ni)
            bf[ni] = *(const s16x8*)&Bs[(wc + ni * 16 + lr) * LDK + lk];
#pragma unroll
        for (int mi = 0; mi < 4; ++mi)
#pragma unroll
            for (int ni = 0; ni < 4; ++ni)
                acc[mi][ni] = __builtin_amdgcn_mfma_f32_16x16x32_bf16(af[mi], bf[ni],
                                                                      acc[mi][ni], 0, 0, 0);
    }

    // C/D layout (m89-verified): col = lane&15, row = (lane>>4)*4 + reg
    const int rb = brow + wr + (lane >> 4) * 4;
    const int cb = bcol + wc + lr;

    if constexpr (MODE == 0) {
        float bv[4];
#pragma unroll
        for (int ni = 0; ni < 4; ++ni) bv[ni] = bias[cb + ni * 16];
#pragma unroll
        for (int mi = 0; mi < 4; ++mi) {
#pragma unroll
            for (int r = 0; r < 4; ++r) {
                int row = rb + mi * 16 + r;
                if (row < N_NODES_C) {
#pragma unroll
                    for (int ni = 0; ni < 4; ++ni) {
                        float v = fmaxf(acc[mi][ni][r] + bv[ni], 0.0f);
                        Cout[(size_t)row * DC + cb + ni * 16] = f2bf(v);
                    }
                }
            }
        }
    } else {
        float bv[4], wv[4];
#pragma unroll
        for (int ni = 0; ni < 4; ++ni) {
            bv[ni] = bias[cb + ni * 16];
            wv[ni] = w2a[cb + ni * 16];
        }
#pragma unroll
        for (int mi = 0; mi < 4; ++mi) {
#pragma unroll
            for (int r = 0; r < 4; ++r) {
                float sum = 0.f;
#pragma unroll
                for (int ni = 0; ni < 4; ++ni) {
                    float v = fmaxf(acc[mi][ni][r] + bv[ni], 0.0f);
                    sum += v * wv[ni];
                }
                // reduce across the 16 column-lanes of this lane group
#pragma unroll
                for (int off = 1; off < 16; off <<= 1) sum += __shfl_xor(sum, off, 64);
                int row = rb + mi * 16 + r;
                if (lr == 0 && row < N_NODES_C) atomicAdd(&s_out[row], sum);
            }
        }
    }
}

// ---------------- launch ----------------

extern "C" void kernel_launch(void* const* d_in, const int* in_sizes, int n_in,
                              void* d_out, int out_size, void* d_ws, size_t ws_size,
                              hipStream_t stream) {
    const float* x     = (const float*)d_in[0];
    const int*   ei    = (const int*)d_in[1];
    const int*   batch = (const int*)d_in[2];
    const float* W1a   = (const float*)d_in[3];
    const float* b1a   = (const float*)d_in[4];
    const float* W1b   = (const float*)d_in[5];
    const float* b1b   = (const float*)d_in[6];
    const float* W2a   = (const float*)d_in[7];
    const float* b2a   = (const float*)d_in[8];
    const float* W2b   = (const float*)d_in[9];
    const float* b2b   = (const float*)d_in[10];
    float* out = (float*)d_out;

    char* w = (char*)d_ws;
    float* z    = (float*)(w);                  // 100000*512*4 = 204,800,000
    short* z1   = (short*)(w + 204800000);      // 100000*512*2 = 102,400,000
    short* WT1  = (short*)(w + 307200000);      // 512*512*2 = 524,288
    short* WT2  = (short*)(w + 307724288);      // 524,288
    float* sbuf = (float*)(w + 308248576);      // 400,000
    float* aggs = (float*)(w + 308648576);      // 400,000
    float* gsum = (float*)(w + 309048576);      // 256
    float* gcnt = (float*)(w + 309048832);      // 256

    zero_k<<<391, 256, 0, stream>>>(sbuf, aggs, gsum, gcnt);
    transpose_w<<<dim3(16, 16), 256, 0, stream>>>(W1a, WT1);
    transpose_w<<<dim3(16, 16), 256, 0, stream>>>(W1b, WT2);
    copy_f4<<<2048, 256, 0, stream>>>(x, z, N_NODES_C * DC / 4);
    scatter_rows<<<N_EDGES_C / 2, 256, 0, stream>>>(x, ei, z);
    gemm_k<0><<<dim3(4, 782), 256, 0, stream>>>(z, WT1, b1a, z1, nullptr, nullptr);
    gemm_k<1><<<dim3(4, 782), 256, 0, stream>>>(z1, WT2, b1b, nullptr, W2a, sbuf);
    edge_scalar<<<586, 256, 0, stream>>>(ei, sbuf, aggs);
    node_pool<<<391, 256, 0, stream>>>(sbuf, aggs, batch, b2a, gsum, gcnt);
    finalize_k<<<1, 64, 0, stream>>>(gsum, gcnt, W2b, b2b, out);
}

// Round 2
// 340.061 us; speedup vs baseline: 3.9129x; 3.9129x over previous
//
#include <hip/hip_runtime.h>
#include <hip/hip_bf16.h>

#define N_NODES_C 100000
#define N_EDGES_C 150000
#define DC 512
#define NG 64

typedef float f32x4 __attribute__((ext_vector_type(4)));
typedef short s16x8 __attribute__((ext_vector_type(8)));
typedef short s16x4 __attribute__((ext_vector_type(4)));

__device__ __forceinline__ short f2bf(float f) {
    union { float f; unsigned u; } c; c.f = f;
    unsigned r = c.u + 0x7fffu + ((c.u >> 16) & 1u);
    return (short)(r >> 16);
}

// ---------------- small kernels ----------------

__global__ void zero_k(float* s, float* aggs, int* cnt, float* gsum, float* gcnt) {
    int i = blockIdx.x * 256 + threadIdx.x;
    if (i < N_NODES_C) { s[i] = 0.f; aggs[i] = 0.f; cnt[i] = 0; }
    if (i < NG) { gsum[i] = 0.f; gcnt[i] = 0.f; }
}

// out[n][k] = bf16(in[k][n]); in is [512][512] f32 row-major
__global__ void transpose_w(const float* __restrict__ in, short* __restrict__ out) {
    __shared__ float tile[32][33];
    int tx = threadIdx.x & 31;
    int ty = threadIdx.x >> 5;  // 0..7
    int k0 = blockIdx.y * 32;
    int n0 = blockIdx.x * 32;
#pragma unroll
    for (int i = 0; i < 4; ++i)
        tile[ty + i * 8][tx] = in[(size_t)(k0 + ty + i * 8) * DC + n0 + tx];
    __syncthreads();
#pragma unroll
    for (int i = 0; i < 4; ++i)
        out[(size_t)(n0 + ty + i * 8) * DC + k0 + tx] = f2bf(tile[tx][ty + i * 8]);
}

// ---------------- counting sort of edges by dst ----------------

__global__ void hist_k(const int* __restrict__ ei, int* __restrict__ cnt) {
    int e = blockIdx.x * 256 + threadIdx.x;
    if (e < N_EDGES_C) atomicAdd(&cnt[ei[N_EDGES_C + e]], 1);
}

// per-block inclusive scan of 1024, exclusive out, block total to bsum
__global__ void scan1_k(const int* __restrict__ cnt, int* __restrict__ off,
                        int* __restrict__ bsum) {
    __shared__ int sh[1024];
    int tid = threadIdx.x;
    int i = blockIdx.x * 1024 + tid;
    int v = (i < N_NODES_C) ? cnt[i] : 0;
    sh[tid] = v;
    __syncthreads();
    for (int d = 1; d < 1024; d <<= 1) {
        int t = (tid >= d) ? sh[tid - d] : 0;
        __syncthreads();
        sh[tid] += t;
        __syncthreads();
    }
    if (i < N_NODES_C) off[i] = sh[tid] - v;  // exclusive
    if (tid == 1023) bsum[blockIdx.x] = sh[1023];
}

#define NSCAN_BLK 98  // ceil(100000/1024)

__global__ void scan2_k(int* __restrict__ bsum) {
    __shared__ int sh[128];
    int tid = threadIdx.x;
    int v = (tid < NSCAN_BLK) ? bsum[tid] : 0;
    sh[tid] = v;
    __syncthreads();
    for (int d = 1; d < 128; d <<= 1) {
        int t = (tid >= d) ? sh[tid - d] : 0;
        __syncthreads();
        sh[tid] += t;
        __syncthreads();
    }
    if (tid < NSCAN_BLK) bsum[tid] = sh[tid] - v;  // exclusive
}

__global__ void scan3_k(int* __restrict__ off, const int* __restrict__ bsum) {
    int i = blockIdx.x * 1024 + threadIdx.x;
    if (i < N_NODES_C) off[i] += bsum[blockIdx.x];
}

// place: off becomes end-cursor; after completion off[i] = start[i+1]
__global__ void place_k(const int* __restrict__ ei, int* __restrict__ off,
                        int* __restrict__ ssrc) {
    int e = blockIdx.x * 256 + threadIdx.x;
    if (e < N_EDGES_C) {
        int d = ei[N_EDGES_C + e];
        int p = atomicAdd(&off[d], 1);
        ssrc[p] = ei[e];
    }
}

// z[i] = bf16(x[i] + sum_{e:dst=i} x[src_e]); 2 nodes/block, 128 threads/node
__global__ void gather_k(const float* __restrict__ x, const int* __restrict__ off,
                         const int* __restrict__ ssrc, short* __restrict__ zb) {
    int node = blockIdx.x * 2 + (threadIdx.x >> 7);
    if (node >= N_NODES_C) return;
    int t = threadIdx.x & 127;
    int beg = (node == 0) ? 0 : off[node - 1];
    int end = off[node];
    f32x4 acc = *(const f32x4*)(x + (size_t)node * DC + t * 4);
    for (int j = beg; j < end; ++j) {
        int s = ssrc[j];
        acc += *(const f32x4*)(x + (size_t)s * DC + t * 4);
    }
    s16x4 r;
    r.x = f2bf(acc.x); r.y = f2bf(acc.y); r.z = f2bf(acc.z); r.w = f2bf(acc.w);
    *(s16x4*)(zb + (size_t)node * DC + t * 4) = r;
}

// ---------------- scalar tail ----------------

__global__ void edge_scalar(const int* __restrict__ ei, const float* __restrict__ s,
                            float* __restrict__ aggs) {
    int e = blockIdx.x * 256 + threadIdx.x;
    if (e < N_EDGES_C) atomicAdd(&aggs[ei[N_EDGES_C + e]], s[ei[e]]);
}

__global__ void node_pool(const float* __restrict__ s, const float* __restrict__ aggs,
                          const int* __restrict__ batch, const float* __restrict__ b2a,
                          float* __restrict__ gsum, float* __restrict__ gcnt) {
    __shared__ float ls[NG], lc[NG];
    int t = threadIdx.x;
    if (t < NG) { ls[t] = 0.f; lc[t] = 0.f; }
    __syncthreads();
    int i = blockIdx.x * 256 + t;
    if (i < N_NODES_C) {
        float z2 = fmaxf(aggs[i] + s[i] + b2a[0], 0.0f);
        int g = batch[i];
        atomicAdd(&ls[g], z2);
        atomicAdd(&lc[g], 1.0f);
    }
    __syncthreads();
    if (t < NG && lc[t] != 0.f) {
        atomicAdd(&gsum[t], ls[t]);
        atomicAdd(&gcnt[t], lc[t]);
    }
}

__global__ void finalize_k(const float* gsum, const float* gcnt, const float* w2b,
                           const float* b2b, float* out) {
    int g = threadIdx.x;
    if (g < NG) {
        float c = fmaxf(gcnt[g], 1.0f);
        out[g] = gsum[g] / c * w2b[0] + b2b[0];
    }
}

// ---------------- GEMM ----------------
// A bf16 [N][512]; B^T bf16 [512 n][512 k]
// EPI 0: C = relu(A@W + bias) -> bf16 Cout
// EPI 1: h = relu(A@W + bias); s_out[row] += h . w2a (no C matrix)
#define BM 128
#define BN 128
#define BK 32
#define LDK 40  // 32 + 8-short pad -> 80B row stride, ~2-way bank aliasing (free)

template <int EPI>
__global__ __launch_bounds__(256, 2) void gemm_k(const short* __restrict__ A,
                                                 const short* __restrict__ Bt,
                                                 const float* __restrict__ bias,
                                                 short* __restrict__ Cout,
                                                 const float* __restrict__ w2a,
                                                 float* __restrict__ s_out) {
    __shared__ alignas(16) short As[BM * LDK];
    __shared__ alignas(16) short Bs[BN * LDK];

    const int tid  = threadIdx.x;
    const int brow = blockIdx.y * BM;
    const int bcol = blockIdx.x * BN;

    const int lane = tid & 63;
    const int wr   = (tid >> 7) * 64;        // wave row
    const int wc   = ((tid >> 6) & 1) * 64;  // wave col
    const int lr   = lane & 15;
    const int lk   = (lane >> 4) * 8;

    f32x4 acc[4][4] = {};

    const int str = tid >> 1;        // staging row/col 0..127
    const int skk = (tid & 1) * 16;  // offset within 32-wide K slab
    int arow = brow + str;
    if (arow >= N_NODES_C) arow = N_NODES_C - 1;  // clamp loads; stores guarded

    const short* agp = A + (size_t)arow * DC + skk;
    const short* bgp = Bt + (size_t)(bcol + str) * DC + skk;

    for (int kt = 0; kt < DC / BK; ++kt) {
        const int k0 = kt * BK;
        s16x8 a0 = *(const s16x8*)(agp + k0);
        s16x8 a1 = *(const s16x8*)(agp + k0 + 8);
        s16x8 b0 = *(const s16x8*)(bgp + k0);
        s16x8 b1 = *(const s16x8*)(bgp + k0 + 8);

        __syncthreads();
        *(s16x8*)&As[str * LDK + skk + 0] = a0;
        *(s16x8*)&As[str * LDK + skk + 8] = a1;
        *(s16x8*)&Bs[str * LDK + skk + 0] = b0;
        *(s16x8*)&Bs[str * LDK + skk + 8] = b1;
        __syncthreads();

        s16x8 af[4], bfr[4];
#pragma unroll
        for (int mi = 0; mi < 4; ++mi)
            af[mi] = *(const s16x8*)&As[(wr + mi * 16 + lr) * LDK + lk];
#pragma unroll
        for (int ni = 0; ni < 4; ++ni)
            bfr[ni] = *(const s16x8*)&Bs[(wc + ni * 16 + lr) * LDK + lk];
#pragma unroll
        for (int mi = 0; mi < 4; ++mi)
#pragma unroll
            for (int ni = 0; ni < 4; ++ni)
                acc[mi][ni] = __builtin_amdgcn_mfma_f32_16x16x32_bf16(af[mi], bfr[ni],
                                                                      acc[mi][ni], 0, 0, 0);
    }

    // C/D layout: col = lane&15, row = (lane>>4)*4 + reg
    const int rb = brow + wr + (lane >> 4) * 4;
    const int cb = bcol + wc + lr;

    if constexpr (EPI == 0) {
        float bv[4];
#pragma unroll
        for (int ni = 0; ni < 4; ++ni) bv[ni] = bias[cb + ni * 16];
#pragma unroll
        for (int mi = 0; mi < 4; ++mi) {
#pragma unroll
            for (int r = 0; r < 4; ++r) {
                int row = rb + mi * 16 + r;
                if (row < N_NODES_C) {
#pragma unroll
                    for (int ni = 0; ni < 4; ++ni) {
                        float v = fmaxf(acc[mi][ni][r] + bv[ni], 0.0f);
                        Cout[(size_t)row * DC + cb + ni * 16] = f2bf(v);
                    }
                }
            }
        }
    } else {
        float bv[4], wv[4];
#pragma unroll
        for (int ni = 0; ni < 4; ++ni) {
            bv[ni] = bias[cb + ni * 16];
            wv[ni] = w2a[cb + ni * 16];
        }
#pragma unroll
        for (int mi = 0; mi < 4; ++mi) {
#pragma unroll
            for (int r = 0; r < 4; ++r) {
                float sum = 0.f;
#pragma unroll
                for (int ni = 0; ni < 4; ++ni) {
                    float v = fmaxf(acc[mi][ni][r] + bv[ni], 0.0f);
                    sum += v * wv[ni];
                }
#pragma unroll
                for (int off = 1; off < 16; off <<= 1) sum += __shfl_xor(sum, off, 64);
                int row = rb + mi * 16 + r;
                if (lr == 0 && row < N_NODES_C) atomicAdd(&s_out[row], sum);
            }
        }
    }
}

// ---------------- launch ----------------

extern "C" void kernel_launch(void* const* d_in, const int* in_sizes, int n_in,
                              void* d_out, int out_size, void* d_ws, size_t ws_size,
                              hipStream_t stream) {
    const float* x     = (const float*)d_in[0];
    const int*   ei    = (const int*)d_in[1];
    const int*   batch = (const int*)d_in[2];
    const float* b1a   = (const float*)d_in[4];
    const float* b1b   = (const float*)d_in[6];
    const float* W2a   = (const float*)d_in[7];
    const float* b2a   = (const float*)d_in[8];
    const float* W2b   = (const float*)d_in[9];
    const float* b2b   = (const float*)d_in[10];
    const float* W1a   = (const float*)d_in[3];
    const float* W1b   = (const float*)d_in[5];
    float* out = (float*)d_out;

    char* w = (char*)d_ws;
    short* zb   = (short*)(w);                  // 100000*512*2 = 102,400,000
    short* z1   = (short*)(w + 102400000);      // 102,400,000
    short* WT1  = (short*)(w + 204800000);      // 524,288
    short* WT2  = (short*)(w + 205324288);      // 524,288
    float* sbuf = (float*)(w + 205848576);      // 400,000
    float* aggs = (float*)(w + 206248576);      // 400,000
    int*   cnt  = (int*)  (w + 206648576);      // 400,000
    int*   offb = (int*)  (w + 207048576);      // 400,000
    int*   ssrc = (int*)  (w + 207448576);      // 600,000
    int*   bsum = (int*)  (w + 208048576);      // 512
    float* gsum = (float*)(w + 208049088);      // 256
    float* gcnt = (float*)(w + 208049344);      // 256

    zero_k<<<391, 256, 0, stream>>>(sbuf, aggs, cnt, gsum, gcnt);
    transpose_w<<<dim3(16, 16), 256, 0, stream>>>(W1a, WT1);
    transpose_w<<<dim3(16, 16), 256, 0, stream>>>(W1b, WT2);

    hist_k<<<586, 256, 0, stream>>>(ei, cnt);
    scan1_k<<<NSCAN_BLK, 1024, 0, stream>>>(cnt, offb, bsum);
    scan2_k<<<1, 128, 0, stream>>>(bsum);
    scan3_k<<<NSCAN_BLK, 1024, 0, stream>>>(offb, bsum);
    place_k<<<586, 256, 0, stream>>>(ei, offb, ssrc);
    gather_k<<<50000, 256, 0, stream>>>(x, offb, ssrc, zb);

    gemm_k<0><<<dim3(4, 782), 256, 0, stream>>>(zb, WT1, b1a, z1, nullptr, nullptr);
    gemm_k<1><<<dim3(4, 782), 256, 0, stream>>>(z1, WT2, b1b, nullptr, W2a, sbuf);

    edge_scalar<<<586, 256, 0, stream>>>(ei, sbuf, aggs);
    node_pool<<<391, 256, 0, stream>>>(sbuf, aggs, batch, b2a, gsum, gcnt);
    finalize_k<<<1, 64, 0, stream>>>(gsum, gcnt, W2b, b2b, out);
}